// Round 4
// baseline (109.360 us; speedup 1.0000x reference)
//
#include <hip/hip_runtime.h>
#include <math.h>

#define N_MID 62
#define BATCH 32768

typedef float f32x4 __attribute__((ext_vector_type(4)));
typedef short s16x8 __attribute__((ext_vector_type(8)));

// fp32 -> bf16 (round-half-up; inputs are positive finite)
__device__ __forceinline__ short f2bf(float f) {
    unsigned u = __float_as_uint(f);
    return (short)((u + 0x8000u) >> 16);
}

// async 16B/lane global -> LDS (wave-uniform LDS base, lane offset = lane*16)
__device__ __forceinline__ void async_copy16(const void* g, void* l) {
    __builtin_amdgcn_global_load_lds(
        (const __attribute__((address_space(1))) void*)g,
        (__attribute__((address_space(3))) void*)l, 16, 0, 0);
}

// ---------------- Kernel 1: spin masks (bit s = x[b,s] > 0) ----------------
__global__ __launch_bounds__(256) void mask_kernel(const int* __restrict__ x,
                                                   unsigned long long* __restrict__ masks) {
    int b = blockIdx.x * 256 + threadIdx.x;
    const int4* xr = (const int4*)(x + (size_t)b * 64);
    unsigned long long m = 0ull;
    #pragma unroll
    for (int c = 0; c < 16; ++c) {
        int4 v = xr[c];
        m |= (unsigned long long)(v.x > 0) << (4 * c + 0);
        m |= (unsigned long long)(v.y > 0) << (4 * c + 1);
        m |= (unsigned long long)(v.z > 0) << (4 * c + 2);
        m |= (unsigned long long)(v.w > 0) << (4 * c + 3);
    }
    masks[b] = m;
}

// ------- Kernel 2: t_mid fp32 -> bf16, pre-swizzled into B-frag order -------
// B-frag layout for mfma_f32_16x16x32_bf16: lane l holds B[k=(l>>4)*8+j][n=l&15].
// wsB frag f = ((site*2+branch)*2 + coltile): 64 lanes x 8 bf16 contiguous.
__global__ __launch_bounds__(64) void bswz_kernel(const float* __restrict__ t_mid,
                                                  short* __restrict__ wsB) {
    int f = blockIdx.x;  // 0..247
    int l = threadIdx.x;
    int t = f & 1, pb = (f >> 1) & 1, s = f >> 2;
    int n = 16 * t + (l & 15);
    int kb = (l >> 4) * 8;
    const float* src = t_mid + (size_t)(s * 2 + pb) * 32 * 32;  // [k][n]
    s16x8 v;
    #pragma unroll
    for (int j = 0; j < 8; ++j) v[j] = f2bf(src[(kb + j) * 32 + n]);
    ((s16x8*)wsB)[f * 64 + l] = v;
}

// ---------------------------- Main MFMA kernel -----------------------------
// One wave = 16 batch elements, states in MFMA C-layout:
//   value (row m, col n) in lane 16*(m>>2) + (n&15), reg (m&3), tile (n>>4).
// Per site: B-frags for the NEXT site async-staged into LDS (shared by the
// block's 4 waves, double-buffered); state -> LDS (bf16, pad-40 rows) ->
// A-frag; 4 MFMAs (2 branches x 2 col-tiles); per-reg branch select; pow2
// rescale every 4 sites with exact log bookkeeping.
#define RSTRIDE 40  // shorts per LDS A-row (80 B, keeps ds_read_b128 aligned)

__global__ __launch_bounds__(256) void mps_mfma_kernel(
    const float* __restrict__ t_first,
    const float* __restrict__ t_last,
    const unsigned long long* __restrict__ masks,
    const short* __restrict__ wsB,
    float* __restrict__ out)
{
    __shared__ short Bst[2][2048];          // 2 bufs x 4 frags x 512 shorts = 8 KB
    __shared__ short Sl[4][16 * RSTRIDE];   // per-wave A-transform scratch

    const int tid  = threadIdx.x;
    const int w    = tid >> 6;       // wave in block (0..3) = frag it stages
    const int l    = tid & 63;       // lane
    const int q    = l >> 4;         // lane group 0..3
    const int p    = l & 15;         // position in group
    const int base = (blockIdx.x * 4 + w) * 16;  // batch tile base

    short* S = &Sl[w][0];

    // Masks for the 4 rows this lane's C-regs cover (rows 4q+r).
    unsigned long long mrot[4];
    #pragma unroll
    for (int r = 0; r < 4; ++r) mrot[r] = masks[base + 4 * q + r];

    // Init state from t_first[bit0]: st[t][r] = value (row 4q+r, col 16t+p)
    float st[2][4];
    #pragma unroll
    for (int r = 0; r < 4; ++r) {
        const float* tf = t_first + ((mrot[r] & 1ull) ? 32 : 0);
        st[0][r] = tf[p];
        st[1][r] = tf[16 + p];
        mrot[r] >>= 1;  // next bit to consume = site 1's bit
    }

    int expsum[4] = {0, 0, 0, 0};

    // Stage site 0's 4 B-frags: wave w loads frag w (1 KB).
    const short* wsBw = wsB + (size_t)w * 512 + l * 8;
    async_copy16(wsBw, &Bst[0][w * 512]);
    __syncthreads();

    int buf = 0;
    for (int s = 0; s < N_MID; ++s) {
        // Async-stage next site's frags into the other buffer.
        if (s < N_MID - 1)
            async_copy16(wsBw + (size_t)(s + 1) * 2048, &Bst[buf ^ 1][w * 512]);

        // State (C-layout regs) -> LDS bf16 [m][k], row stride RSTRIDE.
        #pragma unroll
        for (int r = 0; r < 4; ++r) {
            S[(4 * q + r) * RSTRIDE + p]      = f2bf(st[0][r]);
            S[(4 * q + r) * RSTRIDE + 16 + p] = f2bf(st[1][r]);
        }
        __asm__ volatile("s_waitcnt lgkmcnt(0)" ::: "memory");

        // A-frag: lane reads row m=p, k = 8q..8q+7 (16 B, aligned).
        s16x8 afrag = *(const s16x8*)(S + p * RSTRIDE + 8 * q);

        // B-frags for this site from LDS (conflict-free b128, lane*16B).
        const short* Bb = &Bst[buf][l * 8];
        s16x8 b00 = *(const s16x8*)(Bb);          // branch0 tile0
        s16x8 b01 = *(const s16x8*)(Bb + 512);    // branch0 tile1
        s16x8 b10 = *(const s16x8*)(Bb + 1024);   // branch1 tile0
        s16x8 b11 = *(const s16x8*)(Bb + 1536);   // branch1 tile1

        const f32x4 cz = {0.f, 0.f, 0.f, 0.f};
        f32x4 y0t0 = __builtin_amdgcn_mfma_f32_16x16x32_bf16(afrag, b00, cz, 0, 0, 0);
        f32x4 y0t1 = __builtin_amdgcn_mfma_f32_16x16x32_bf16(afrag, b01, cz, 0, 0, 0);
        f32x4 y1t0 = __builtin_amdgcn_mfma_f32_16x16x32_bf16(afrag, b10, cz, 0, 0, 0);
        f32x4 y1t1 = __builtin_amdgcn_mfma_f32_16x16x32_bf16(afrag, b11, cz, 0, 0, 0);

        // Per-row branch select by this site's spin bit.
        #pragma unroll
        for (int r = 0; r < 4; ++r) {
            bool hi = (mrot[r] & 1ull) != 0;
            st[0][r] = hi ? y1t0[r] : y0t0[r];
            st[1][r] = hi ? y1t1[r] : y0t1[r];
            mrot[r] >>= 1;
        }

        // Power-of-2 per-row rescale every 4 sites (exact log bookkeeping).
        if ((s & 3) == 3) {
            #pragma unroll
            for (int r = 0; r < 4; ++r) {
                float mx = fmaxf(st[0][r], st[1][r]);
                #pragma unroll
                for (int off = 1; off < 16; off <<= 1)
                    mx = fmaxf(mx, __shfl_xor(mx, off, 16));
                int ex = (int)((__float_as_uint(mx) >> 23) & 0xFF) - 127;
                float scale = __uint_as_float((unsigned)(127 - ex) << 23);
                st[0][r] *= scale;
                st[1][r] *= scale;
                expsum[r] += ex;
            }
        }

        // Barrier: drains the async stage (vmcnt) + syncs buffer swap.
        __syncthreads();
        buf ^= 1;
    }

    // Epilogue: amp_r = dot(state_r, t_last[bit63]); reduce over 16 lanes.
    float tl00 = t_last[p],      tl01 = t_last[16 + p];
    float tl10 = t_last[32 + p], tl11 = t_last[48 + p];
    float amp[4];
    #pragma unroll
    for (int r = 0; r < 4; ++r) {
        bool hi = (mrot[r] & 1ull) != 0;  // bit 63 after 63 shifts
        float prod = st[0][r] * (hi ? tl10 : tl00) + st[1][r] * (hi ? tl11 : tl01);
        #pragma unroll
        for (int off = 1; off < 16; off <<= 1)
            prod += __shfl_xor(prod, off, 16);
        amp[r] = prod;
    }

    if (p < 4) {
        float a = (p == 0) ? amp[0] : (p == 1) ? amp[1] : (p == 2) ? amp[2] : amp[3];
        int   e = (p == 0) ? expsum[0] : (p == 1) ? expsum[1] : (p == 2) ? expsum[2] : expsum[3];
        out[base + 4 * q + p] = logf(a) + 0.69314718055994531f * (float)e;
    }
}

extern "C" void kernel_launch(void* const* d_in, const int* in_sizes, int n_in,
                              void* d_out, int out_size, void* d_ws, size_t ws_size,
                              hipStream_t stream) {
    const float* t_first = (const float*)d_in[0];
    const float* t_mid   = (const float*)d_in[1];
    const float* t_last  = (const float*)d_in[2];
    const int*   x       = (const int*)d_in[3];
    float* out           = (float*)d_out;

    unsigned long long* masks = (unsigned long long*)d_ws;            // 256 KB
    short* wsB = (short*)((char*)d_ws + (size_t)BATCH * 8);           // 248 KB

    hipLaunchKernelGGL(mask_kernel, dim3(BATCH / 256), dim3(256), 0, stream, x, masks);
    hipLaunchKernelGGL(bswz_kernel, dim3(N_MID * 4), dim3(64), 0, stream, t_mid, wsB);
    hipLaunchKernelGGL(mps_mfma_kernel, dim3(BATCH / 64), dim3(256), 0, stream,
                       t_first, t_last, masks, wsB, out);
}

// Round 5
// 86.768 us; speedup vs baseline: 1.2604x; 1.2604x over previous
//
#include <hip/hip_runtime.h>
#include <math.h>

#define N_MID 62
#define BATCH 32768
#define RSTRIDE 40  // shorts per LDS A-row (80 B; keeps b128 reads 16B-aligned)

typedef float f32x4 __attribute__((ext_vector_type(4)));
typedef short s16x8 __attribute__((ext_vector_type(8)));

// fp32 -> bf16 (round-half-up; inputs positive finite)
__device__ __forceinline__ short f2bf(float f) {
    unsigned u = __float_as_uint(f);
    return (short)((u + 0x8000u) >> 16);
}
// pack two fp32 -> dword of two bf16 (lo=a, hi=b)
__device__ __forceinline__ unsigned pack_bf(float a, float b) {
    unsigned ua = __float_as_uint(a), ub = __float_as_uint(b);
    return ((ua + 0x8000u) >> 16) | ((ub + 0x8000u) & 0xFFFF0000u);
}

// ---------- Prefix kernel: masks + t_mid bf16 B-frag swizzle (merged) ------
// Blocks 0..247: B-swizzle. Frag f=(site*2+branch)*2+tile; lane l holds
// B[k=(l>>4)*8+j][n=l&15] where k is the PERMUTED index: the A-side packs
// state pairs (orig n, orig 16+n) into dwords, so new-k 2d <-> orig d,
// 2d+1 <-> orig 16+d. Blocks 248..759: spin masks (bit s = x[b,s] > 0).
__global__ __launch_bounds__(64) void prefix_kernel(const float* __restrict__ t_mid,
                                                    const int* __restrict__ x,
                                                    short* __restrict__ wsB,
                                                    unsigned long long* __restrict__ masks) {
    int l = threadIdx.x;
    if (blockIdx.x < 248) {
        int f = blockIdx.x;
        int t = f & 1, pb = (f >> 1) & 1, s = f >> 2;
        int n = 16 * t + (l & 15);
        int kb = (l >> 4) * 8;
        const float* src = t_mid + (size_t)(s * 2 + pb) * 1024;  // [k][n]
        s16x8 v;
        #pragma unroll
        for (int j = 0; j < 8; ++j) {
            int kappa = kb + j;
            int ok = (kappa & 1) ? 16 + (kappa >> 1) : (kappa >> 1);
            v[j] = f2bf(src[ok * 32 + n]);
        }
        ((s16x8*)wsB)[f * 64 + l] = v;
    } else {
        int b = (blockIdx.x - 248) * 64 + l;
        const int4* xr = (const int4*)(x + (size_t)b * 64);
        unsigned long long m = 0ull;
        #pragma unroll
        for (int c = 0; c < 16; ++c) {
            int4 v = xr[c];
            m |= (unsigned long long)(v.x > 0) << (4 * c + 0);
            m |= (unsigned long long)(v.y > 0) << (4 * c + 1);
            m |= (unsigned long long)(v.z > 0) << (4 * c + 2);
            m |= (unsigned long long)(v.w > 0) << (4 * c + 3);
        }
        masks[b] = m;
    }
}

// ---------------------------- Main MFMA kernel -----------------------------
// One wave = 16 batch elements, barrier-free. States in MFMA C-layout:
//   value (row m, col n) at lane 16*(m>>2)+(n&15), reg m&3, tile n>>4.
// Per site: lgkmcnt wait -> A-frag b128 read -> 4 MFMAs (2 branches x 2
// col-tiles, B-frags prefetched 2 sites ahead from L2) -> per-reg branch
// select -> (every 8 sites: pow2 rescale, exact log bookkeeping) -> packed
// b32 state writes for the next site.
__global__ __launch_bounds__(256) void mps_mfma_kernel(
    const float* __restrict__ t_first,
    const float* __restrict__ t_last,
    const unsigned long long* __restrict__ masks,
    const short* __restrict__ wsB,
    float* __restrict__ out)
{
    __shared__ short Sl[4][16 * RSTRIDE];  // per-wave private scratch, 1280 B

    const int tid  = threadIdx.x;
    const int w    = tid >> 6;
    const int l    = tid & 63;
    const int q    = l >> 4;
    const int p    = l & 15;
    const int base = (blockIdx.x * 4 + w) * 16;

    short* S = &Sl[w][0];

    unsigned long long mrot[4];
    #pragma unroll
    for (int r = 0; r < 4; ++r) mrot[r] = masks[base + 4 * q + r];

    // B-frag prefetch: slot0 = even sites, slot1 = odd sites.
    const s16x8* bpb = (const s16x8*)wsB + l;
    s16x8 B0[4], B1[4];
    #pragma unroll
    for (int f = 0; f < 4; ++f) B0[f] = bpb[f * 64];
    #pragma unroll
    for (int f = 0; f < 4; ++f) B1[f] = bpb[256 + f * 64];

    // Init state from t_first[bit0], write packed to LDS.
    float st[2][4];
    #pragma unroll
    for (int r = 0; r < 4; ++r) {
        const float* tf = t_first + ((mrot[r] & 1ull) ? 32 : 0);
        st[0][r] = tf[p];
        st[1][r] = tf[16 + p];
        mrot[r] >>= 1;
        ((unsigned*)(S + (4 * q + r) * RSTRIDE))[p] = pack_bf(st[0][r], st[1][r]);
    }

    int expsum[4] = {0, 0, 0, 0};
    const f32x4 cz = {0.f, 0.f, 0.f, 0.f};

    auto site = [&](s16x8* Bb, const s16x8* pf, bool resc) {
        __asm__ volatile("s_waitcnt lgkmcnt(0)" ::: "memory");
        s16x8 afrag = *(const s16x8*)(S + p * RSTRIDE + 8 * q);

        f32x4 y00 = __builtin_amdgcn_mfma_f32_16x16x32_bf16(afrag, Bb[0], cz, 0, 0, 0);
        f32x4 y01 = __builtin_amdgcn_mfma_f32_16x16x32_bf16(afrag, Bb[1], cz, 0, 0, 0);
        f32x4 y10 = __builtin_amdgcn_mfma_f32_16x16x32_bf16(afrag, Bb[2], cz, 0, 0, 0);
        f32x4 y11 = __builtin_amdgcn_mfma_f32_16x16x32_bf16(afrag, Bb[3], cz, 0, 0, 0);

        if (pf) {  // prefetch this slot's next site (2 ahead), L2-resident
            #pragma unroll
            for (int f = 0; f < 4; ++f) Bb[f] = pf[f * 64];
        }

        #pragma unroll
        for (int r = 0; r < 4; ++r) {
            bool hi = (mrot[r] & 1ull) != 0;
            st[0][r] = hi ? y10[r] : y00[r];
            st[1][r] = hi ? y11[r] : y01[r];
            mrot[r] >>= 1;
        }

        if (resc) {  // power-of-2 per-row rescale, exact log bookkeeping
            #pragma unroll
            for (int r = 0; r < 4; ++r) {
                float mx = fmaxf(st[0][r], st[1][r]);
                #pragma unroll
                for (int off = 1; off < 16; off <<= 1)
                    mx = fmaxf(mx, __shfl_xor(mx, off, 16));
                int ex = (int)((__float_as_uint(mx) >> 23) & 0xFF) - 127;
                float sc = __uint_as_float((unsigned)(127 - ex) << 23);
                st[0][r] *= sc;
                st[1][r] *= sc;
                expsum[r] += ex;
            }
        }

        #pragma unroll
        for (int r = 0; r < 4; ++r)
            ((unsigned*)(S + (4 * q + r) * RSTRIDE))[p] = pack_bf(st[0][r], st[1][r]);
    };

    const s16x8* pref = bpb + 512;  // site 2 base
    for (int s2 = 0; s2 < 30; ++s2) {
        site(B0, pref, false);                    // site 2*s2
        site(B1, pref + 256, (s2 & 3) == 3);      // site 2*s2+1 (rescale at 7,15,..,55)
        pref += 512;
    }
    site(B0, nullptr, false);  // site 60
    site(B1, nullptr, false);  // site 61

    // Epilogue: amp_r = dot(state_r, t_last[bit63]); 16-lane reduce.
    float tl00 = t_last[p],      tl01 = t_last[16 + p];
    float tl10 = t_last[32 + p], tl11 = t_last[48 + p];
    float amp[4];
    #pragma unroll
    for (int r = 0; r < 4; ++r) {
        bool hi = (mrot[r] & 1ull) != 0;
        float prod = st[0][r] * (hi ? tl10 : tl00) + st[1][r] * (hi ? tl11 : tl01);
        #pragma unroll
        for (int off = 1; off < 16; off <<= 1)
            prod += __shfl_xor(prod, off, 16);
        amp[r] = prod;
    }

    if (p < 4) {
        float a = (p == 0) ? amp[0] : (p == 1) ? amp[1] : (p == 2) ? amp[2] : amp[3];
        int   e = (p == 0) ? expsum[0] : (p == 1) ? expsum[1] : (p == 2) ? expsum[2] : expsum[3];
        out[base + 4 * q + p] = logf(a) + 0.69314718055994531f * (float)e;
    }
}

extern "C" void kernel_launch(void* const* d_in, const int* in_sizes, int n_in,
                              void* d_out, int out_size, void* d_ws, size_t ws_size,
                              hipStream_t stream) {
    const float* t_first = (const float*)d_in[0];
    const float* t_mid   = (const float*)d_in[1];
    const float* t_last  = (const float*)d_in[2];
    const int*   x       = (const int*)d_in[3];
    float* out           = (float*)d_out;

    unsigned long long* masks = (unsigned long long*)d_ws;            // 256 KB
    short* wsB = (short*)((char*)d_ws + (size_t)BATCH * 8);           // 248 KB

    hipLaunchKernelGGL(prefix_kernel, dim3(248 + BATCH / 64), dim3(64), 0, stream,
                       t_mid, x, wsB, masks);
    hipLaunchKernelGGL(mps_mfma_kernel, dim3(BATCH / 64), dim3(256), 0, stream,
                       t_first, t_last, masks, wsB, out);
}

// Round 6
// 83.513 us; speedup vs baseline: 1.3095x; 1.0390x over previous
//
#include <hip/hip_runtime.h>
#include <math.h>

#define N_MID 62
#define BATCH 32768

typedef float f32x4 __attribute__((ext_vector_type(4)));
typedef short s16x8 __attribute__((ext_vector_type(8)));
typedef unsigned int u32x4 __attribute__((ext_vector_type(4)));

// fp32 -> bf16 round-half-up (prefix only; inputs positive finite)
__device__ __forceinline__ short f2bf(float f) {
    unsigned u = __float_as_uint(f);
    return (short)((u + 0x8000u) >> 16);
}

// ---- Prefix: t_mid fp32 -> bf16 A-frags with component relabeling ----------
// Frag f = (site*2 + branch)*2 + tile. MFMA A-layout (16x16x32, verified):
// lane l holds A[m=l&15][k=(l>>4)*8+j]. We need A_t[m,k] = T[lam(k)][16t+m]
// where lam(8q+j) = 16*(j>>2) + 4q + (j&3)  (the relabeling that makes the
// main loop's C->B transform purely in-lane).
__global__ __launch_bounds__(64) void prefix_kernel(const float* __restrict__ t_mid,
                                                    short* __restrict__ wsA) {
    int f = blockIdx.x;              // 0..247
    int l = threadIdx.x;
    int t = f & 1, b = (f >> 1) & 1, s = f >> 2;
    int q = l >> 4, m = l & 15;
    const float* src = t_mid + (size_t)(s * 2 + b) * 1024;  // T[k][n] 32x32
    s16x8 v;
    #pragma unroll
    for (int j = 0; j < 8; ++j) {
        int lam = 16 * (j >> 2) + 4 * q + (j & 3);
        v[j] = f2bf(src[lam * 32 + 16 * t + m]);
    }
    ((s16x8*)wsA)[f * 64 + l] = v;
}

// ---------------------------- Main MFMA kernel -----------------------------
// One wave = 16 batch elements (element = lane&15), NO LDS, no barriers.
// State lives as a B-fragment in registers: B slot (q=l>>4, j) holds
// s_e[16*(j>>2)+4q+(j&3)]. Per site: 4 MFMAs (A = T-frags for 2 branches x
// 2 col-tiles, prefetched 2 sites ahead); D col = lane&15 = element, so the
// branch select is one lane-uniform cndmask set; D regs (r,t) pack straight
// back into B slots j=4t+r with 4 v_perm instructions.
__global__ __launch_bounds__(256) void mps_mfma_kernel(
    const float* __restrict__ t_first,
    const float* __restrict__ t_last,
    const int*   __restrict__ x,
    const short* __restrict__ wsA,
    float* __restrict__ out)
{
    const int tid  = threadIdx.x;
    const int w    = tid >> 6;
    const int l    = tid & 63;
    const int q    = l >> 4;
    const int e    = l & 15;
    const int base = (blockIdx.x * 4 + w) * 16;

    // ---- Inline spin mask for element e: bit s = (x[base+e][s] > 0). ----
    // Lane (q,e) builds bits 16q..16q+15, then OR-reduce across the 4 q-lanes.
    unsigned long long mask;
    {
        const int4* xr = (const int4*)(x + (size_t)(base + e) * 64 + 16 * q);
        unsigned chunk = 0;
        #pragma unroll
        for (int c = 0; c < 4; ++c) {
            int4 v = xr[c];
            chunk |= (unsigned)(v.x > 0) << (4 * c + 0);
            chunk |= (unsigned)(v.y > 0) << (4 * c + 1);
            chunk |= (unsigned)(v.z > 0) << (4 * c + 2);
            chunk |= (unsigned)(v.w > 0) << (4 * c + 3);
        }
        unsigned sh = chunk << ((q & 1) * 16);
        unsigned lo = (q < 2) ? sh : 0u;
        unsigned hi = (q >= 2) ? sh : 0u;
        lo |= (unsigned)__shfl_xor((int)lo, 16);
        lo |= (unsigned)__shfl_xor((int)lo, 32);
        hi |= (unsigned)__shfl_xor((int)hi, 16);
        hi |= (unsigned)__shfl_xor((int)hi, 32);
        mask = ((unsigned long long)hi << 32) | lo;
    }

    // ---- Init state as B-frag from t_first[bit0]. ----
    float st[8];
    {
        const float* tf = t_first + ((mask & 1ull) ? 32 : 0);
        #pragma unroll
        for (int j = 0; j < 8; ++j)
            st[j] = tf[16 * (j >> 2) + 4 * q + (j & 3)];
    }
    unsigned long long mrot = mask >> 1;

    s16x8 Bst;
    {
        u32x4 bp;
        #pragma unroll
        for (int d = 0; d < 4; ++d)
            bp[d] = __builtin_amdgcn_perm(__float_as_uint(st[2 * d + 1]),
                                          __float_as_uint(st[2 * d]), 0x07060302u);
        Bst = __builtin_bit_cast(s16x8, bp);
    }

    int expsum = 0;
    const f32x4 cz = {0.f, 0.f, 0.f, 0.f};

    // A-frag slots: A0 = even sites, A1 = odd sites (prefetch 2 ahead).
    const s16x8* bpa = (const s16x8*)wsA + l;
    s16x8 A0[4], A1[4];
    #pragma unroll
    for (int f = 0; f < 4; ++f) A0[f] = bpa[f * 64];
    #pragma unroll
    for (int f = 0; f < 4; ++f) A1[f] = bpa[(4 + f) * 64];

    auto site = [&](s16x8* A, const s16x8* pf, bool resc) {
        f32x4 y00 = __builtin_amdgcn_mfma_f32_16x16x32_bf16(A[0], Bst, cz, 0, 0, 0);
        f32x4 y01 = __builtin_amdgcn_mfma_f32_16x16x32_bf16(A[1], Bst, cz, 0, 0, 0);
        f32x4 y10 = __builtin_amdgcn_mfma_f32_16x16x32_bf16(A[2], Bst, cz, 0, 0, 0);
        f32x4 y11 = __builtin_amdgcn_mfma_f32_16x16x32_bf16(A[3], Bst, cz, 0, 0, 0);

        if (pf) {
            #pragma unroll
            for (int f = 0; f < 4; ++f) A[f] = pf[f * 64];
        }

        bool hi = (mrot & 1ull) != 0;
        mrot >>= 1;
        #pragma unroll
        for (int r = 0; r < 4; ++r) {
            st[r]     = hi ? y10[r] : y00[r];   // tile 0 -> j = r
            st[4 + r] = hi ? y11[r] : y01[r];   // tile 1 -> j = 4 + r
        }

        if (resc) {  // per-element pow2 rescale, exact log bookkeeping
            float mx = st[0];
            #pragma unroll
            for (int j = 1; j < 8; ++j) mx = fmaxf(mx, st[j]);
            mx = fmaxf(mx, __shfl_xor(mx, 16));
            mx = fmaxf(mx, __shfl_xor(mx, 32));
            int ex = (int)((__float_as_uint(mx) >> 23) & 0xFF) - 127;
            float sc = __uint_as_float((unsigned)(127 - ex) << 23);
            #pragma unroll
            for (int j = 0; j < 8; ++j) st[j] *= sc;
            expsum += ex;
        }

        u32x4 bp;
        #pragma unroll
        for (int d = 0; d < 4; ++d)
            bp[d] = __builtin_amdgcn_perm(__float_as_uint(st[2 * d + 1]),
                                          __float_as_uint(st[2 * d]), 0x07060302u);
        Bst = __builtin_bit_cast(s16x8, bp);
    };

    const s16x8* pf = bpa + 8 * 64;  // site-2 frags
    for (int s2 = 0; s2 < 31; ++s2) {
        bool more = (s2 < 30);
        site(A0, more ? pf : nullptr, false);
        site(A1, more ? pf + 4 * 64 : nullptr, (s2 & 3) == 3);
        pf += 8 * 64;
    }

    // ---- Epilogue: amp_e = dot(state_e, t_last[bit63]); reduce over q. ----
    const float* tl = t_last + ((mrot & 1ull) ? 32 : 0);
    float amp = 0.f;
    #pragma unroll
    for (int j = 0; j < 8; ++j)
        amp = fmaf(st[j], tl[16 * (j >> 2) + 4 * q + (j & 3)], amp);
    amp += __shfl_xor(amp, 16);
    amp += __shfl_xor(amp, 32);

    if (l < 16)
        out[base + l] = logf(amp) + 0.69314718055994531f * (float)expsum;
}

extern "C" void kernel_launch(void* const* d_in, const int* in_sizes, int n_in,
                              void* d_out, int out_size, void* d_ws, size_t ws_size,
                              hipStream_t stream) {
    const float* t_first = (const float*)d_in[0];
    const float* t_mid   = (const float*)d_in[1];
    const float* t_last  = (const float*)d_in[2];
    const int*   x       = (const int*)d_in[3];
    float* out           = (float*)d_out;

    short* wsA = (short*)d_ws;  // 248 KB of bf16 A-frags

    hipLaunchKernelGGL(prefix_kernel, dim3(N_MID * 4), dim3(64), 0, stream, t_mid, wsA);
    hipLaunchKernelGGL(mps_mfma_kernel, dim3(BATCH / 64), dim3(256), 0, stream,
                       t_first, t_last, x, wsA, out);
}